// Round 5
// baseline (543.564 us; speedup 1.0000x reference)
//
#include <hip/hip_runtime.h>
#include <cstdint>

typedef uint16_t u16;
typedef uint32_t u32;
typedef uint64_t u64;
typedef __attribute__((ext_vector_type(4))) float f32x4;
typedef __attribute__((ext_vector_type(8))) short bf16x8;

__device__ __forceinline__ u16 f2bf(float f) {
  union { float f; u32 i; } u; u.f = f;
  u32 r = u.i + 0x7FFFu + ((u.i >> 16) & 1u);
  return (u16)(r >> 16);
}
__device__ __forceinline__ float sigm(float x) { return 1.f / (1.f + __expf(-x)); }

// ---------------- K0: pre-pack fin_w f32 -> bf16 (GEMM B operand) --------
__global__ __launch_bounds__(256) void k0_pack(
    const float* __restrict__ fw, u16* __restrict__ fwb)
{
  int i = blockIdx.x * 256 + threadIdx.x;
  f32x4 v = ((const f32x4*)fw)[i];
  u64 p = (u64)f2bf(v[0]) | ((u64)f2bf(v[1]) << 16) |
          ((u64)f2bf(v[2]) << 32) | ((u64)f2bf(v[3]) << 48);
  ((u64*)fwb)[i] = p;
}

// ---------------- K1: r = relu(bn(conv1x1(gate))) , fp32 out -------------
__global__ __launch_bounds__(256) void k1_reduce(
    const float* __restrict__ x, const float* __restrict__ rw, const float* __restrict__ rb,
    const float* __restrict__ bg, const float* __restrict__ bb, const float* __restrict__ bm,
    const float* __restrict__ bv, float* __restrict__ r)
{
  __shared__ __align__(16) float wl[256][16];
  __shared__ float bl[16];
  __shared__ float sl[16];
  int t = threadIdx.x;
  if (t < 16) {
    float s = bg[t] * rsqrtf(bv[t] + 1e-5f);
    sl[t] = s;
    bl[t] = (rb[t] - bm[t]) * s + bb[t];
  }
  __syncthreads();
  for (int i = 0; i < 16; ++i) {
    int flat = i * 256 + t;
    int co = flat >> 8, c = flat & 255;
    wl[c][co] = rw[co * 256 + c] * sl[co];
  }
  __syncthreads();
  int p = blockIdx.x * 256 + t;
  int b = p >> 12, pp = p & 4095;
  const float* gsrc = x + ((size_t)(b * 512 + 256)) * 4096 + pp;
  float acc[16];
#pragma unroll
  for (int co = 0; co < 16; ++co) acc[co] = bl[co];
#pragma unroll 4
  for (int c = 0; c < 256; ++c) {
    float g = gsrc[(size_t)c * 4096];
    const f32x4* wr = (const f32x4*)(&wl[c][0]);
    f32x4 a0 = wr[0], a1 = wr[1], a2 = wr[2], a3 = wr[3];
    acc[0]  += g * a0[0]; acc[1]  += g * a0[1]; acc[2]  += g * a0[2]; acc[3]  += g * a0[3];
    acc[4]  += g * a1[0]; acc[5]  += g * a1[1]; acc[6]  += g * a1[2]; acc[7]  += g * a1[3];
    acc[8]  += g * a2[0]; acc[9]  += g * a2[1]; acc[10] += g * a2[2]; acc[11] += g * a2[3];
    acc[12] += g * a3[0]; acc[13] += g * a3[1]; acc[14] += g * a3[2]; acc[15] += g * a3[3];
  }
  float* rd = r + ((size_t)b * 16) * 4096 + pp;
#pragma unroll
  for (int co = 0; co < 16; ++co) rd[(size_t)co * 4096] = fmaxf(acc[co], 0.f);
}

// ---------------- K2: means over h / w / both ----------------------------
__global__ __launch_bounds__(64) void k2_means(
    const float* __restrict__ r, float* __restrict__ cm, float* __restrict__ rm,
    float* __restrict__ ctx)
{
  int bc = blockIdx.x, t = threadIdx.x;
  const float* src = r + (size_t)bc * 4096;
  float cs = 0.f;
  for (int h = 0; h < 64; ++h) {
    float v = src[h * 64 + t];
    cs += v;
    float s = v;
#pragma unroll
    for (int m = 32; m; m >>= 1) s += __shfl_xor(s, m, 64);
    if (t == h) rm[bc * 64 + h] = s * (1.f / 64.f);
  }
  cm[bc * 64 + t] = cs * (1.f / 64.f);
  float tot = cs;
#pragma unroll
  for (int m = 32; m; m >>= 1) tot += __shfl_xor(tot, m, 64);
  if (t == 0) ctx[bc] = tot * (1.f / 4096.f);
}

// ---------------- K3a: gct weights + attn (DWT path collapses to ctx) ----
__global__ __launch_bounds__(256) void k3a_gct(
    const float* __restrict__ ctx,
    const float* f1w, const float* f1b, const float* lng, const float* lnb,
    const float* f2w, const float* f2b, const float* fcw, const float* fcb,
    float* __restrict__ wgct, float* __restrict__ attn)
{
  __shared__ float cl[256];
  __shared__ float gl[256];
  int t = threadIdx.x;
  cl[t] = ctx[t];
  __syncthreads();
  int b = t >> 4, c = t & 15;
  const float* cb = &cl[b * 16];
  float a[4];
#pragma unroll
  for (int j = 0; j < 4; ++j) {
    float s = f1b[j];
    for (int i = 0; i < 16; ++i) s += cb[i] * f1w[j * 16 + i];
    a[j] = s;
  }
  float mu = 0.25f * (a[0] + a[1] + a[2] + a[3]);
  float var = 0.f;
#pragma unroll
  for (int j = 0; j < 4; ++j) { float d = a[j] - mu; var += d * d; }
  var *= 0.25f;
  float inv = rsqrtf(var + 1e-5f);
#pragma unroll
  for (int j = 0; j < 4; ++j)
    a[j] = fmaxf((a[j] - mu) * inv * lng[j] + lnb[j], 0.f);
  float s2 = f2b[c];
#pragma unroll
  for (int j = 0; j < 4; ++j) s2 += a[j] * f2w[c * 4 + j];
  wgct[t] = sigm(s2);
  float g = fcb[c];
  for (int i = 0; i < 16; ++i) g += cb[i] * fcw[c * 16 + i];
  gl[t] = g;
  __syncthreads();
  const float* gb = &gl[b * 16];
  float mx = -1e30f;
  for (int i = 0; i < 16; ++i) mx = fmaxf(mx, gb[i]);
  float den = 0.f;
  for (int i = 0; i < 16; ++i) den += __expf(gb[i] - mx);
  attn[t] = __expf(g - mx) / den;
}

// ---------------- K3b: rel h/v 1D convs -> hfc[b,o,w], vfc[b,o,h] --------
__global__ __launch_bounds__(64) void k3b_rel(
    const float* __restrict__ cm, const float* __restrict__ rm,
    const float* hw, const float* hb, const float* hbg, const float* hbb, const float* hbm, const float* hbv,
    const float* vw, const float* vb_, const float* vbg, const float* vbb, const float* vbm, const float* vbv,
    const float* fw, const float* fb, float* __restrict__ hfc, float* __restrict__ vfc)
{
  __shared__ float cml[16][64], rml[16][64];
  int b = blockIdx.x, t = threadIdx.x;
  for (int i = 0; i < 16; ++i) {
    cml[i][t] = cm[(b * 16 + i) * 64 + t];
    rml[i][t] = rm[(b * 16 + i) * 64 + t];
  }
  __syncthreads();
  float hf[8], vf[8];
  for (int o = 0; o < 8; ++o) {
    float sh = 0.f, sv = 0.f;
    for (int ci = 0; ci < 16; ++ci) {
#pragma unroll
      for (int kk = 0; kk < 3; ++kk) {
        int q = t + kk - 1;
        bool ok = (q >= 0 && q < 64);
        int qi = ok ? q : 0;
        float xh = ok ? cml[ci][qi] : 0.f;
        float xv = ok ? rml[ci][qi] : 0.f;
        sh += hw[(o * 16 + ci) * 3 + kk] * xh;
        sv += vw[(o * 16 + ci) * 3 + kk] * xv;
      }
    }
    float s1 = hbg[o] * rsqrtf(hbv[o] + 1e-5f);
    hf[o] = fmaxf((sh + hb[o] - hbm[o]) * s1 + hbb[o], 0.f);
    float s2 = vbg[o] * rsqrtf(vbv[o] + 1e-5f);
    vf[o] = fmaxf((sv + vb_[o] - vbm[o]) * s2 + vbb[o], 0.f);
  }
  for (int o = 0; o < 16; ++o) {
    float sh = fb[o], sv = 0.f;   // fus bias folded into hfc only
#pragma unroll
    for (int c = 0; c < 8; ++c) {
      sh += fw[o * 16 + c] * hf[c];
      sv += fw[o * 16 + 8 + c] * vf[c];
    }
    hfc[(b * 16 + o) * 64 + t] = sh;
    vfc[(b * 16 + o) * 64 + t] = sv;
  }
}

// ---------------- K45: fused gate + fin GEMM per (b,h); f32 output -------
// grid 1024 (b*64+h) x 256 thr (4 waves; wave wv owns n-strip wv*128..+128)
__global__ __launch_bounds__(256) void k45_fused(
    const float* __restrict__ x, const float* __restrict__ r,
    const float* __restrict__ wgct, const float* __restrict__ attn,
    const float* __restrict__ hfc, const float* __restrict__ vfc,
    const float* sfw, const float* sfb, const float* sg, const float* sb_,
    const float* sm, const float* sv,
    const u16* __restrict__ fwb, const float* __restrict__ fb,
    float* __restrict__ out)
{
  __shared__ __align__(16) char region0[67584];   // A[64][520] u16 | Dsh[256][66] f32
  __shared__ __align__(16) float wsf[256][16];
  __shared__ float inter[16][64];
  __shared__ float bsf[256];
  __shared__ float wg[16], at[16], vfh[16];
  u16* A = (u16*)region0;
  float* Dsh = (float*)region0;

  int bid = blockIdx.x;
  int b = bid >> 6, h = bid & 63;
  int t = threadIdx.x;

  // phase 0: identity transpose into A[w][c] (c<256), params into LDS
  for (int i = 0; i < 16; ++i) {
    int flat = i * 256 + t;           // 4096 = 256c x 16 float4
    int c = flat >> 4, q = flat & 15;
    f32x4 v = *(const f32x4*)(x + ((size_t)(b * 512 + c)) * 4096 + h * 64 + q * 4);
#pragma unroll
    for (int j = 0; j < 4; ++j) A[(q * 4 + j) * 520 + c] = f2bf(v[j]);
  }
  if (t < 16) {
    wg[t] = wgct[b * 16 + t];
    at[t] = attn[b * 16 + t];
    vfh[t] = vfc[(b * 16 + t) * 64 + h];
  }
  {
    int o = t;
    float s = sg[o] * rsqrtf(sv[o] + 1e-5f);
    bsf[o] = (sfb[o] - sm[o]) * s + sb_[o];
#pragma unroll
    for (int k2 = 0; k2 < 16; ++k2) wsf[o][k2] = sfw[o * 16 + k2] * s;
  }
  __syncthreads();

  // interaction[k][w] = r^2*wgct*rel + r*attn
  for (int i = 0; i < 4; ++i) {
    int idx = i * 256 + t;
    int k = idx >> 6, w = idx & 63;
    float rv = r[((size_t)(b * 16 + k)) * 4096 + h * 64 + w];
    float rel = sigm(hfc[(b * 16 + k) * 64 + w] + vfh[k]);
    inter[k][w] = rv * rv * wg[k] * rel + rv * at[k];
  }
  __syncthreads();

  // gated half: A[w][256+o] = bf16(gate * sigmoid(bn(sf conv)))
  {
    int w = t & 63, og = t >> 6;
    float iv[16];
#pragma unroll
    for (int k2 = 0; k2 < 16; ++k2) iv[k2] = inter[k2][w];
    const float* gsrc = x + ((size_t)(b * 512 + 256)) * 4096 + h * 64 + w;
    for (int j = 0; j < 64; ++j) {
      int o = og * 64 + j;
      const f32x4* wr = (const f32x4*)(&wsf[o][0]);
      f32x4 w0 = wr[0], w1 = wr[1], w2 = wr[2], w3 = wr[3];
      float dot = bsf[o];
      dot += iv[0] * w0[0] + iv[1] * w0[1] + iv[2] * w0[2] + iv[3] * w0[3];
      dot += iv[4] * w1[0] + iv[5] * w1[1] + iv[6] * w1[2] + iv[7] * w1[3];
      dot += iv[8] * w2[0] + iv[9] * w2[1] + iv[10] * w2[2] + iv[11] * w2[3];
      dot += iv[12] * w3[0] + iv[13] * w3[1] + iv[14] * w3[2] + iv[15] * w3[3];
      float gwv = sigm(dot);
      float gv = gsrc[(size_t)o * 4096];
      A[w * 520 + 256 + o] = f2bf(gv * gwv);
    }
  }
  __syncthreads();

  // GEMM: out_tile[w][n] = sum_k A[w][k] * fwb[n][k] + fb[n]
  int lane = t & 63, wv = t >> 6;
  int fr = lane & 15, quad = lane >> 4;
  int n0w = wv * 128;
  f32x4 acc[4][8];
#pragma unroll
  for (int j = 0; j < 8; ++j) {
    float bvv = fb[n0w + j * 16 + fr];
    f32x4 b4 = {bvv, bvv, bvv, bvv};
#pragma unroll
    for (int i = 0; i < 4; ++i) acc[i][j] = b4;
  }
  for (int kb = 0; kb < 16; ++kb) {
    int c0 = kb * 32 + quad * 8;
    bf16x8 af[4];
#pragma unroll
    for (int i = 0; i < 4; ++i)
      af[i] = *(const bf16x8*)(A + (i * 16 + fr) * 520 + c0);
#pragma unroll
    for (int j = 0; j < 8; ++j) {
      bf16x8 bfr = *(const bf16x8*)(fwb + (size_t)(n0w + j * 16 + fr) * 512 + c0);
#pragma unroll
      for (int i = 0; i < 4; ++i)
        acc[i][j] = __builtin_amdgcn_mfma_f32_16x16x32_bf16(af[i], bfr, acc[i][j], 0, 0, 0);
    }
  }

  // epilogue: two n-halves of 256; Dsh[256][66] f32 -> coalesced f32 stores
  for (int half = 0; half < 2; ++half) {
    __syncthreads();
    if ((wv >> 1) == half) {
#pragma unroll
      for (int j = 0; j < 8; ++j) {
        int nl = n0w - half * 256 + j * 16 + fr;
#pragma unroll
        for (int i = 0; i < 4; ++i)
#pragma unroll
          for (int rg = 0; rg < 4; ++rg)
            Dsh[nl * 66 + i * 16 + quad * 4 + rg] = acc[i][j][rg];
      }
    }
    __syncthreads();
    for (int it = 0; it < 64; ++it) {
      int flat = it * 256 + t;          // 256 rows x 64 f32
      int nl = flat >> 6, md = flat & 63;
      float d = Dsh[nl * 66 + md];
      out[((size_t)(b * 512 + half * 256 + nl)) * 4096 + h * 64 + md] = d;
    }
  }
}

extern "C" void kernel_launch(void* const* d_in, const int* in_sizes, int n_in,
                              void* d_out, int out_size, void* d_ws, size_t ws_size,
                              hipStream_t stream) {
  const float* x      = (const float*)d_in[0];
  const float* red_w  = (const float*)d_in[1];
  const float* red_b  = (const float*)d_in[2];
  const float* rbg    = (const float*)d_in[3];
  const float* rbb    = (const float*)d_in[4];
  const float* rbm    = (const float*)d_in[5];
  const float* rbv    = (const float*)d_in[6];
  const float* f1w    = (const float*)d_in[7];
  const float* f1b    = (const float*)d_in[8];
  const float* lng    = (const float*)d_in[9];
  const float* lnb    = (const float*)d_in[10];
  const float* f2w    = (const float*)d_in[11];
  const float* f2b    = (const float*)d_in[12];
  const float* rhw    = (const float*)d_in[13];
  const float* rhb    = (const float*)d_in[14];
  const float* rhbg   = (const float*)d_in[15];
  const float* rhbb   = (const float*)d_in[16];
  const float* rhbm   = (const float*)d_in[17];
  const float* rhbv   = (const float*)d_in[18];
  const float* rvw    = (const float*)d_in[19];
  const float* rvb    = (const float*)d_in[20];
  const float* rvbg   = (const float*)d_in[21];
  const float* rvbb   = (const float*)d_in[22];
  const float* rvbm   = (const float*)d_in[23];
  const float* rvbv   = (const float*)d_in[24];
  const float* fusw   = (const float*)d_in[25];
  const float* fusb   = (const float*)d_in[26];
  // d_in[27] hw_theta, d_in[28] hw_fuse_w: provably no effect on output
  const float* fcw    = (const float*)d_in[29];
  const float* fcb    = (const float*)d_in[30];
  const float* sfw    = (const float*)d_in[31];
  const float* sfb    = (const float*)d_in[32];
  const float* sbg    = (const float*)d_in[33];
  const float* sbb    = (const float*)d_in[34];
  const float* sbm    = (const float*)d_in[35];
  const float* sbv    = (const float*)d_in[36];
  const float* finw   = (const float*)d_in[37];
  const float* finb   = (const float*)d_in[38];
  float* out = (float*)d_out;   // reference output dtype is float32

  char* ws = (char*)d_ws;
  size_t off = 0;
  float* r   = (float*)(ws + off); off += (size_t)16 * 16 * 4096 * 4;   // 4 MB
  u16*   fwb = (u16*)(ws + off);   off += (size_t)512 * 512 * 2;        // 512 KB
  float* cm  = (float*)(ws + off); off += 65536;
  float* rm  = (float*)(ws + off); off += 65536;
  float* ctx = (float*)(ws + off); off += 1024;
  float* wg  = (float*)(ws + off); off += 1024;
  float* at  = (float*)(ws + off); off += 1024;
  float* hfc = (float*)(ws + off); off += 65536;
  float* vfc = (float*)(ws + off); off += 65536;

  k0_pack<<<256, 256, 0, stream>>>(finw, fwb);
  k1_reduce<<<256, 256, 0, stream>>>(x, red_w, red_b, rbg, rbb, rbm, rbv, r);
  k2_means<<<256, 64, 0, stream>>>(r, cm, rm, ctx);
  k3a_gct<<<1, 256, 0, stream>>>(ctx, f1w, f1b, lng, lnb, f2w, f2b, fcw, fcb, wg, at);
  k3b_rel<<<16, 64, 0, stream>>>(cm, rm, rhw, rhb, rhbg, rhbb, rhbm, rhbv,
                                 rvw, rvb, rvbg, rvbb, rvbm, rvbv, fusw, fusb, hfc, vfc);
  k45_fused<<<1024, 256, 0, stream>>>(x, r, wg, at, hfc, vfc,
                                      sfw, sfb, sbg, sbb, sbm, sbv, fwb, finb, out);
}

// Round 6
// 512.002 us; speedup vs baseline: 1.0616x; 1.0616x over previous
//
#include <hip/hip_runtime.h>
#include <cstdint>

typedef uint16_t u16;
typedef uint32_t u32;
typedef uint64_t u64;
typedef __attribute__((ext_vector_type(4))) float f32x4;
typedef __attribute__((ext_vector_type(8))) short bf16x8;

__device__ __forceinline__ u16 f2bf(float f) {
  union { float f; u32 i; } u; u.f = f;
  u32 r = u.i + 0x7FFFu + ((u.i >> 16) & 1u);
  return (u16)(r >> 16);
}
__device__ __forceinline__ float sigm(float x) { return 1.f / (1.f + __expf(-x)); }

// ---------------- K0: pre-pack fin_w f32 -> bf16 (GEMM B operand) --------
__global__ __launch_bounds__(256) void k0_pack(
    const float* __restrict__ fw, u16* __restrict__ fwb)
{
  int i = blockIdx.x * 256 + threadIdx.x;
  f32x4 v = ((const f32x4*)fw)[i];
  u64 p = (u64)f2bf(v[0]) | ((u64)f2bf(v[1]) << 16) |
          ((u64)f2bf(v[2]) << 32) | ((u64)f2bf(v[3]) << 48);
  ((u64*)fwb)[i] = p;
}

// ---------------- K1: r = relu(bn(conv1x1(gate))) , fp32 out -------------
__global__ __launch_bounds__(256) void k1_reduce(
    const float* __restrict__ x, const float* __restrict__ rw, const float* __restrict__ rb,
    const float* __restrict__ bg, const float* __restrict__ bb, const float* __restrict__ bm,
    const float* __restrict__ bv, float* __restrict__ r)
{
  __shared__ __align__(16) float wl[256][16];
  __shared__ float bl[16];
  __shared__ float sl[16];
  int t = threadIdx.x;
  if (t < 16) {
    float s = bg[t] * rsqrtf(bv[t] + 1e-5f);
    sl[t] = s;
    bl[t] = (rb[t] - bm[t]) * s + bb[t];
  }
  __syncthreads();
  for (int i = 0; i < 16; ++i) {
    int flat = i * 256 + t;
    int co = flat >> 8, c = flat & 255;
    wl[c][co] = rw[co * 256 + c] * sl[co];
  }
  __syncthreads();
  int p = blockIdx.x * 256 + t;
  int b = p >> 12, pp = p & 4095;
  const float* gsrc = x + ((size_t)(b * 512 + 256)) * 4096 + pp;
  float acc[16];
#pragma unroll
  for (int co = 0; co < 16; ++co) acc[co] = bl[co];
#pragma unroll 4
  for (int c = 0; c < 256; ++c) {
    float g = gsrc[(size_t)c * 4096];
    const f32x4* wr = (const f32x4*)(&wl[c][0]);
    f32x4 a0 = wr[0], a1 = wr[1], a2 = wr[2], a3 = wr[3];
    acc[0]  += g * a0[0]; acc[1]  += g * a0[1]; acc[2]  += g * a0[2]; acc[3]  += g * a0[3];
    acc[4]  += g * a1[0]; acc[5]  += g * a1[1]; acc[6]  += g * a1[2]; acc[7]  += g * a1[3];
    acc[8]  += g * a2[0]; acc[9]  += g * a2[1]; acc[10] += g * a2[2]; acc[11] += g * a2[3];
    acc[12] += g * a3[0]; acc[13] += g * a3[1]; acc[14] += g * a3[2]; acc[15] += g * a3[3];
  }
  float* rd = r + ((size_t)b * 16) * 4096 + pp;
#pragma unroll
  for (int co = 0; co < 16; ++co) rd[(size_t)co * 4096] = fmaxf(acc[co], 0.f);
}

// ---------------- K2: means over h / w / both (LDS-staged) ---------------
// grid 256 (b*16+c) x 256 thr
__global__ __launch_bounds__(256) void k2_means(
    const float* __restrict__ r, float* __restrict__ cm, float* __restrict__ rm,
    float* __restrict__ ctx)
{
  __shared__ __align__(16) float tile[64][68];
  int bc = blockIdx.x, t = threadIdx.x;
  const float* src = r + (size_t)bc * 4096;
#pragma unroll
  for (int i = 0; i < 4; ++i) {
    int off = (i * 256 + t) * 4;
    int row = off >> 6, col = off & 63;
    f32x4 v = *(const f32x4*)(src + off);
    *(f32x4*)&tile[row][col] = v;
  }
  __syncthreads();
  int wv = t >> 6, lane = t & 63;
  if (wv == 0) {
    float s = 0.f;
    for (int h = 0; h < 64; ++h) s += tile[h][lane];
    cm[bc * 64 + lane] = s * (1.f / 64.f);
    float tot = s;
#pragma unroll
    for (int m = 32; m; m >>= 1) tot += __shfl_xor(tot, m, 64);
    if (lane == 0) ctx[bc] = tot * (1.f / 4096.f);
  } else if (wv == 1) {
    float s = 0.f;
    for (int w0 = 0; w0 < 64; ++w0) s += tile[lane][(w0 + lane) & 63];
    rm[bc * 64 + lane] = s * (1.f / 64.f);
  }
}

// ---------------- K3a: gct weights + attn (DWT path collapses to ctx) ----
__global__ __launch_bounds__(256) void k3a_gct(
    const float* __restrict__ ctx,
    const float* f1w, const float* f1b, const float* lng, const float* lnb,
    const float* f2w, const float* f2b, const float* fcw, const float* fcb,
    float* __restrict__ wgct, float* __restrict__ attn)
{
  __shared__ float cl[256];
  __shared__ float gl[256];
  int t = threadIdx.x;
  cl[t] = ctx[t];
  __syncthreads();
  int b = t >> 4, c = t & 15;
  const float* cb = &cl[b * 16];
  float a[4];
#pragma unroll
  for (int j = 0; j < 4; ++j) {
    float s = f1b[j];
    for (int i = 0; i < 16; ++i) s += cb[i] * f1w[j * 16 + i];
    a[j] = s;
  }
  float mu = 0.25f * (a[0] + a[1] + a[2] + a[3]);
  float var = 0.f;
#pragma unroll
  for (int j = 0; j < 4; ++j) { float d = a[j] - mu; var += d * d; }
  var *= 0.25f;
  float inv = rsqrtf(var + 1e-5f);
#pragma unroll
  for (int j = 0; j < 4; ++j)
    a[j] = fmaxf((a[j] - mu) * inv * lng[j] + lnb[j], 0.f);
  float s2 = f2b[c];
#pragma unroll
  for (int j = 0; j < 4; ++j) s2 += a[j] * f2w[c * 4 + j];
  wgct[t] = sigm(s2);
  float g = fcb[c];
  for (int i = 0; i < 16; ++i) g += cb[i] * fcw[c * 16 + i];
  gl[t] = g;
  __syncthreads();
  const float* gb = &gl[b * 16];
  float mx = -1e30f;
  for (int i = 0; i < 16; ++i) mx = fmaxf(mx, gb[i]);
  float den = 0.f;
  for (int i = 0; i < 16; ++i) den += __expf(gb[i] - mx);
  attn[t] = __expf(g - mx) / den;
}

// ---------------- K3b: rel h/v 1D convs -> hfc[b,o,w], vfc[b,o,h] --------
__global__ __launch_bounds__(64) void k3b_rel(
    const float* __restrict__ cm, const float* __restrict__ rm,
    const float* hw, const float* hb, const float* hbg, const float* hbb, const float* hbm, const float* hbv,
    const float* vw, const float* vb_, const float* vbg, const float* vbb, const float* vbm, const float* vbv,
    const float* fw, const float* fb, float* __restrict__ hfc, float* __restrict__ vfc)
{
  __shared__ float cml[16][64], rml[16][64];
  int b = blockIdx.x, t = threadIdx.x;
  for (int i = 0; i < 16; ++i) {
    cml[i][t] = cm[(b * 16 + i) * 64 + t];
    rml[i][t] = rm[(b * 16 + i) * 64 + t];
  }
  __syncthreads();
  float hf[8], vf[8];
  for (int o = 0; o < 8; ++o) {
    float sh = 0.f, sv = 0.f;
    for (int ci = 0; ci < 16; ++ci) {
#pragma unroll
      for (int kk = 0; kk < 3; ++kk) {
        int q = t + kk - 1;
        bool ok = (q >= 0 && q < 64);
        int qi = ok ? q : 0;
        float xh = ok ? cml[ci][qi] : 0.f;
        float xv = ok ? rml[ci][qi] : 0.f;
        sh += hw[(o * 16 + ci) * 3 + kk] * xh;
        sv += vw[(o * 16 + ci) * 3 + kk] * xv;
      }
    }
    float s1 = hbg[o] * rsqrtf(hbv[o] + 1e-5f);
    hf[o] = fmaxf((sh + hb[o] - hbm[o]) * s1 + hbb[o], 0.f);
    float s2 = vbg[o] * rsqrtf(vbv[o] + 1e-5f);
    vf[o] = fmaxf((sv + vb_[o] - vbm[o]) * s2 + vbb[o], 0.f);
  }
  for (int o = 0; o < 16; ++o) {
    float sh = fb[o], sv = 0.f;   // fus bias folded into hfc only
#pragma unroll
    for (int c = 0; c < 8; ++c) {
      sh += fw[o * 16 + c] * hf[c];
      sv += fw[o * 16 + 8 + c] * vf[c];
    }
    hfc[(b * 16 + o) * 64 + t] = sh;
    vfc[(b * 16 + o) * 64 + t] = sv;
  }
}

// ---------------- K4p: gate pipeline -> pack P[m][512] bf16 --------------
// grid 1024 (b*64+h) x 256 thr; LDS ~55 KB -> 2 blocks/CU
__global__ __launch_bounds__(256) void k4_pack(
    const float* __restrict__ x, const float* __restrict__ r,
    const float* __restrict__ wgct, const float* __restrict__ attn,
    const float* __restrict__ hfc, const float* __restrict__ vfc,
    const float* sfw, const float* sfb, const float* sg, const float* sb_,
    const float* sm, const float* sv, u16* __restrict__ P)
{
  __shared__ float inter[16][64];
  __shared__ __align__(16) float wsf[256][16];
  __shared__ float bsf[256];
  __shared__ float wg[16], at[16], vfh[16];
  __shared__ __align__(16) u16 t2[64][258];
  int bid = blockIdx.x;
  int b = bid >> 6, h = bid & 63;
  int t = threadIdx.x;

  // identity transpose f32 -> bf16 into t2[w][c]
  for (int i = 0; i < 16; ++i) {
    int flat = i * 256 + t;
    int c = flat >> 4, q = flat & 15;
    f32x4 v = *(const f32x4*)(x + ((size_t)(b * 512 + c)) * 4096 + h * 64 + q * 4);
#pragma unroll
    for (int j = 0; j < 4; ++j) t2[q * 4 + j][c] = f2bf(v[j]);
  }
  if (t < 16) {
    wg[t] = wgct[b * 16 + t];
    at[t] = attn[b * 16 + t];
    vfh[t] = vfc[(b * 16 + t) * 64 + h];
  }
  {
    int o = t;
    float s = sg[o] * rsqrtf(sv[o] + 1e-5f);
    bsf[o] = (sfb[o] - sm[o]) * s + sb_[o];
#pragma unroll
    for (int k2 = 0; k2 < 16; ++k2) wsf[o][k2] = sfw[o * 16 + k2] * s;
  }
  __syncthreads();
  // dump identity half: P[m][0..255]
  for (int i = 0; i < 32; ++i) {
    int flat = i * 256 + t;
    int wr = flat >> 7, cd = flat & 127;
    u32 d = *(const u32*)((const char*)t2 + wr * 516 + cd * 4);
    ((u32*)(P + ((size_t)(b * 4096 + h * 64 + wr)) * 512))[cd] = d;
  }
  // interaction[k][w]
  for (int i = 0; i < 4; ++i) {
    int idx = i * 256 + t;
    int k = idx >> 6, w = idx & 63;
    float rv = r[((size_t)(b * 16 + k)) * 4096 + h * 64 + w];
    float rel = sigm(hfc[(b * 16 + k) * 64 + w] + vfh[k]);
    inter[k][w] = rv * rv * wg[k] * rel + rv * at[k];
  }
  __syncthreads();
  // gated half -> t2[w][o]
  {
    int w = t & 63, og = t >> 6;
    float iv[16];
#pragma unroll
    for (int k2 = 0; k2 < 16; ++k2) iv[k2] = inter[k2][w];
    const float* gsrc = x + ((size_t)(b * 512 + 256)) * 4096 + h * 64 + w;
    for (int j = 0; j < 64; ++j) {
      int o = og * 64 + j;
      const f32x4* wr = (const f32x4*)(&wsf[o][0]);
      f32x4 w0 = wr[0], w1 = wr[1], w2 = wr[2], w3 = wr[3];
      float dot = bsf[o];
      dot += iv[0] * w0[0] + iv[1] * w0[1] + iv[2] * w0[2] + iv[3] * w0[3];
      dot += iv[4] * w1[0] + iv[5] * w1[1] + iv[6] * w1[2] + iv[7] * w1[3];
      dot += iv[8] * w2[0] + iv[9] * w2[1] + iv[10] * w2[2] + iv[11] * w2[3];
      dot += iv[12] * w3[0] + iv[13] * w3[1] + iv[14] * w3[2] + iv[15] * w3[3];
      float gwv = sigm(dot);
      float gv = gsrc[(size_t)o * 4096];
      t2[w][o] = f2bf(gv * gwv);
    }
  }
  __syncthreads();
  // dump gated half: P[m][256..511]
  for (int i = 0; i < 32; ++i) {
    int flat = i * 256 + t;
    int wr = flat >> 7, cd = flat & 127;
    u32 d = *(const u32*)((const char*)t2 + wr * 516 + cd * 4);
    ((u32*)(P + ((size_t)(b * 4096 + h * 64 + wr)) * 512 + 256))[cd] = d;
  }
}

// ---------------- K5: pure MFMA GEMM, A resident in LDS ------------------
// grid 1024 (b*64+h) x 256 thr; LDS 67.6 KB -> 2 blocks/CU; no k-loop barriers
__global__ __launch_bounds__(256) void k5_gemm(
    const u16* __restrict__ P, const u16* __restrict__ fwb,
    const float* __restrict__ fb, float* __restrict__ out)
{
  __shared__ __align__(16) char region[67584];  // A[64][528] u16 | Dsh[128][66] f32
  u16* A = (u16*)region;
  float* Dsh = (float*)region;
  int bid = blockIdx.x;
  int b = bid >> 6, h = bid & 63;
  int t = threadIdx.x;
  int lane = t & 63, wv = t >> 6;
  int fr = lane & 15, quad = lane >> 4;

  // stage A (coalesced 1 KB/inst; LDS writes row-contiguous, conflict-free)
  const u16* Pb = P + (size_t)bid * 64 * 512;
#pragma unroll
  for (int i = 0; i < 16; ++i) {
    int pix = i * 4 + wv;
    bf16x8 v = *(const bf16x8*)(Pb + (size_t)pix * 512 + lane * 8);
    *(bf16x8*)(A + pix * 528 + lane * 8) = v;
  }
  int n0w = wv * 128;
  f32x4 acc[4][8];
#pragma unroll
  for (int j = 0; j < 8; ++j) {
    float bvv = fb[n0w + j * 16 + fr];
    f32x4 b4 = {bvv, bvv, bvv, bvv};
#pragma unroll
    for (int i = 0; i < 4; ++i) acc[i][j] = b4;
  }
  __syncthreads();

  for (int kb = 0; kb < 16; ++kb) {
    int c0 = kb * 32 + quad * 8;
    bf16x8 af[4];
#pragma unroll
    for (int i = 0; i < 4; ++i)
      af[i] = *(const bf16x8*)(A + (i * 16 + fr) * 528 + c0);
#pragma unroll
    for (int j = 0; j < 8; ++j) {
      bf16x8 bfr = *(const bf16x8*)(fwb + (size_t)(n0w + j * 16 + fr) * 512 + c0);
#pragma unroll
      for (int i = 0; i < 4; ++i)
        acc[i][j] = __builtin_amdgcn_mfma_f32_16x16x32_bf16(af[i], bfr, acc[i][j], 0, 0, 0);
    }
  }
  __syncthreads();   // A reads done before Dsh overwrite

  // epilogue: 4 passes (one wave's n-strip each), coalesced f32 stores
  for (int q = 0; q < 4; ++q) {
    if (wv == q) {
#pragma unroll
      for (int j = 0; j < 8; ++j) {
        int nl = j * 16 + fr;
#pragma unroll
        for (int i = 0; i < 4; ++i)
#pragma unroll
          for (int rg = 0; rg < 4; ++rg)
            Dsh[nl * 66 + i * 16 + quad * 4 + rg] = acc[i][j][rg];
      }
    }
    __syncthreads();
    for (int it = 0; it < 32; ++it) {
      int flat = it * 256 + t;
      int nl = flat >> 6, md = flat & 63;
      out[((size_t)(b * 512 + q * 128 + nl)) * 4096 + h * 64 + md] = Dsh[nl * 66 + md];
    }
    __syncthreads();
  }
}

// ---------------- fallback: R5's fused kernel (passed; used if ws small) -
__global__ __launch_bounds__(256) void k45_fused(
    const float* __restrict__ x, const float* __restrict__ r,
    const float* __restrict__ wgct, const float* __restrict__ attn,
    const float* __restrict__ hfc, const float* __restrict__ vfc,
    const float* sfw, const float* sfb, const float* sg, const float* sb_,
    const float* sm, const float* sv,
    const u16* __restrict__ fwb, const float* __restrict__ fb,
    float* __restrict__ out)
{
  __shared__ __align__(16) char region0[67584];
  __shared__ __align__(16) float wsf[256][16];
  __shared__ float inter[16][64];
  __shared__ float bsf[256];
  __shared__ float wg[16], at[16], vfh[16];
  u16* A = (u16*)region0;
  float* Dsh = (float*)region0;

  int bid = blockIdx.x;
  int b = bid >> 6, h = bid & 63;
  int t = threadIdx.x;

  for (int i = 0; i < 16; ++i) {
    int flat = i * 256 + t;
    int c = flat >> 4, q = flat & 15;
    f32x4 v = *(const f32x4*)(x + ((size_t)(b * 512 + c)) * 4096 + h * 64 + q * 4);
#pragma unroll
    for (int j = 0; j < 4; ++j) A[(q * 4 + j) * 520 + c] = f2bf(v[j]);
  }
  if (t < 16) {
    wg[t] = wgct[b * 16 + t];
    at[t] = attn[b * 16 + t];
    vfh[t] = vfc[(b * 16 + t) * 64 + h];
  }
  {
    int o = t;
    float s = sg[o] * rsqrtf(sv[o] + 1e-5f);
    bsf[o] = (sfb[o] - sm[o]) * s + sb_[o];
#pragma unroll
    for (int k2 = 0; k2 < 16; ++k2) wsf[o][k2] = sfw[o * 16 + k2] * s;
  }
  __syncthreads();
  for (int i = 0; i < 4; ++i) {
    int idx = i * 256 + t;
    int k = idx >> 6, w = idx & 63;
    float rv = r[((size_t)(b * 16 + k)) * 4096 + h * 64 + w];
    float rel = sigm(hfc[(b * 16 + k) * 64 + w] + vfh[k]);
    inter[k][w] = rv * rv * wg[k] * rel + rv * at[k];
  }
  __syncthreads();
  {
    int w = t & 63, og = t >> 6;
    float iv[16];
#pragma unroll
    for (int k2 = 0; k2 < 16; ++k2) iv[k2] = inter[k2][w];
    const float* gsrc = x + ((size_t)(b * 512 + 256)) * 4096 + h * 64 + w;
    for (int j = 0; j < 64; ++j) {
      int o = og * 64 + j;
      const f32x4* wr = (const f32x4*)(&wsf[o][0]);
      f32x4 w0 = wr[0], w1 = wr[1], w2 = wr[2], w3 = wr[3];
      float dot = bsf[o];
      dot += iv[0] * w0[0] + iv[1] * w0[1] + iv[2] * w0[2] + iv[3] * w0[3];
      dot += iv[4] * w1[0] + iv[5] * w1[1] + iv[6] * w1[2] + iv[7] * w1[3];
      dot += iv[8] * w2[0] + iv[9] * w2[1] + iv[10] * w2[2] + iv[11] * w2[3];
      dot += iv[12] * w3[0] + iv[13] * w3[1] + iv[14] * w3[2] + iv[15] * w3[3];
      float gwv = sigm(dot);
      float gv = gsrc[(size_t)o * 4096];
      A[w * 520 + 256 + o] = f2bf(gv * gwv);
    }
  }
  __syncthreads();

  int lane = t & 63, wv = t >> 6;
  int fr = lane & 15, quad = lane >> 4;
  int n0w = wv * 128;
  f32x4 acc[4][8];
#pragma unroll
  for (int j = 0; j < 8; ++j) {
    float bvv = fb[n0w + j * 16 + fr];
    f32x4 b4 = {bvv, bvv, bvv, bvv};
#pragma unroll
    for (int i = 0; i < 4; ++i) acc[i][j] = b4;
  }
  for (int kb = 0; kb < 16; ++kb) {
    int c0 = kb * 32 + quad * 8;
    bf16x8 af[4];
#pragma unroll
    for (int i = 0; i < 4; ++i)
      af[i] = *(const bf16x8*)(A + (i * 16 + fr) * 520 + c0);
#pragma unroll
    for (int j = 0; j < 8; ++j) {
      bf16x8 bfr = *(const bf16x8*)(fwb + (size_t)(n0w + j * 16 + fr) * 512 + c0);
#pragma unroll
      for (int i = 0; i < 4; ++i)
        acc[i][j] = __builtin_amdgcn_mfma_f32_16x16x32_bf16(af[i], bfr, acc[i][j], 0, 0, 0);
    }
  }
  for (int half = 0; half < 2; ++half) {
    __syncthreads();
    if ((wv >> 1) == half) {
#pragma unroll
      for (int j = 0; j < 8; ++j) {
        int nl = n0w - half * 256 + j * 16 + fr;
#pragma unroll
        for (int i = 0; i < 4; ++i)
#pragma unroll
          for (int rg = 0; rg < 4; ++rg)
            Dsh[nl * 66 + i * 16 + quad * 4 + rg] = acc[i][j][rg];
      }
    }
    __syncthreads();
    for (int it = 0; it < 64; ++it) {
      int flat = it * 256 + t;
      int nl = flat >> 6, md = flat & 63;
      float d = Dsh[nl * 66 + md];
      out[((size_t)(b * 512 + half * 256 + nl)) * 4096 + h * 64 + md] = d;
    }
  }
}

extern "C" void kernel_launch(void* const* d_in, const int* in_sizes, int n_in,
                              void* d_out, int out_size, void* d_ws, size_t ws_size,
                              hipStream_t stream) {
  const float* x      = (const float*)d_in[0];
  const float* red_w  = (const float*)d_in[1];
  const float* red_b  = (const float*)d_in[2];
  const float* rbg    = (const float*)d_in[3];
  const float* rbb    = (const float*)d_in[4];
  const float* rbm    = (const float*)d_in[5];
  const float* rbv    = (const float*)d_in[6];
  const float* f1w    = (const float*)d_in[7];
  const float* f1b    = (const float*)d_in[8];
  const float* lng    = (const float*)d_in[9];
  const float* lnb    = (const float*)d_in[10];
  const float* f2w    = (const float*)d_in[11];
  const float* f2b    = (const float*)d_in[12];
  const float* rhw    = (const float*)d_in[13];
  const float* rhb    = (const float*)d_in[14];
  const float* rhbg   = (const float*)d_in[15];
  const float* rhbb   = (const float*)d_in[16];
  const float* rhbm   = (const float*)d_in[17];
  const float* rhbv   = (const float*)d_in[18];
  const float* rvw    = (const float*)d_in[19];
  const float* rvb    = (const float*)d_in[20];
  const float* rvbg   = (const float*)d_in[21];
  const float* rvbb   = (const float*)d_in[22];
  const float* rvbm   = (const float*)d_in[23];
  const float* rvbv   = (const float*)d_in[24];
  const float* fusw   = (const float*)d_in[25];
  const float* fusb   = (const float*)d_in[26];
  const float* fcw    = (const float*)d_in[29];
  const float* fcb    = (const float*)d_in[30];
  const float* sfw    = (const float*)d_in[31];
  const float* sfb    = (const float*)d_in[32];
  const float* sbg    = (const float*)d_in[33];
  const float* sbb    = (const float*)d_in[34];
  const float* sbm    = (const float*)d_in[35];
  const float* sbv    = (const float*)d_in[36];
  const float* finw   = (const float*)d_in[37];
  const float* finb   = (const float*)d_in[38];
  float* out = (float*)d_out;

  char* ws = (char*)d_ws;
  size_t off = 0;
  float* r   = (float*)(ws + off); off += (size_t)16 * 16 * 4096 * 4;   // 4 MB
  u16*   fwb = (u16*)(ws + off);   off += (size_t)512 * 512 * 2;        // 512 KB
  float* cm  = (float*)(ws + off); off += 65536;
  float* rm  = (float*)(ws + off); off += 65536;
  float* ctx = (float*)(ws + off); off += 1024;
  float* wg  = (float*)(ws + off); off += 1024;
  float* at  = (float*)(ws + off); off += 1024;
  float* hfc = (float*)(ws + off); off += 65536;
  float* vfc = (float*)(ws + off); off += 65536;
  u16*   P   = (u16*)(ws + off);
  size_t need = off + (size_t)65536 * 512 * 2;                          // +64 MB
  bool split = (ws_size >= need);

  k0_pack<<<256, 256, 0, stream>>>(finw, fwb);
  k1_reduce<<<256, 256, 0, stream>>>(x, red_w, red_b, rbg, rbb, rbm, rbv, r);
  k2_means<<<256, 256, 0, stream>>>(r, cm, rm, ctx);
  k3a_gct<<<1, 256, 0, stream>>>(ctx, f1w, f1b, lng, lnb, f2w, f2b, fcw, fcb, wg, at);
  k3b_rel<<<16, 64, 0, stream>>>(cm, rm, rhw, rhb, rhbg, rhbb, rhbm, rhbv,
                                 rvw, rvb, rvbg, rvbb, rvbm, rvbv, fusw, fusb, hfc, vfc);
  if (split) {
    k4_pack<<<1024, 256, 0, stream>>>(x, r, wg, at, hfc, vfc,
                                      sfw, sfb, sbg, sbb, sbm, sbv, P);
    k5_gemm<<<1024, 256, 0, stream>>>(P, fwb, finb, out);
  } else {
    k45_fused<<<1024, 256, 0, stream>>>(x, r, wg, at, hfc, vfc,
                                        sfw, sfb, sbg, sbb, sbm, sbv, fwb, finb, out);
  }
}